// Round 4
// baseline (3748.721 us; speedup 1.0000x reference)
//
#include <hip/hip_runtime.h>
#include <math.h>

// Problem constants (B=8, T=256 -> 2048 independent (b,t) pipelines)
#define NBT 2048

typedef __attribute__((ext_vector_type(8))) short short8;     // 8 bf16 (4 VGPRs)
typedef __attribute__((ext_vector_type(4))) float floatx4;    // MFMA C/D

struct SM {
  alignas(16) float xp[240];      // zero-padded encoder input (nonzero in [80,160))
  alignas(16) unsigned xhl[256];  // packed bf16: hi | lo<<16, zero-padded to 256
  alignas(16) float hsq[256];     // h^2 for top-64 ranking
  alignas(16) float hsel[256];    // masked hidden vector (decode input)
  alignas(16) float yres[80];
  alignas(16) float beL[256];     // encoder bias staged in LDS
  float xres[80];
  float yal[80];
  float xele[80];
  float decsrc[80];
  float zb[80];
  float spad[238];                // padded buffer for sim windows
  float energy[96];               // 81 valid + pad to 96 (6 m-tiles of 16)
  float epart4[384];              // 4 waves x 96 rows of per-wave energy partials
  float mp_self[256];
  float mp_src[256];
  float ext[160];
  float red[4];
  int   redi[4];
  unsigned char smask[80];
  int smask_t;
};

__device__ __forceinline__ float warpSum(float v){
  #pragma unroll
  for (int off = 32; off > 0; off >>= 1) v += __shfl_down(v, off, 64);
  return v;
}

__device__ __forceinline__ float blockSum(SM& sm, float v){
  v = warpSum(v);
  int wave = threadIdx.x >> 6;
  __syncthreads();                     // protect red[] from previous use
  if ((threadIdx.x & 63) == 0) sm.red[wave] = v;
  __syncthreads();
  return sm.red[0] + sm.red[1] + sm.red[2] + sm.red[3];
}

__device__ __forceinline__ float blockMax(SM& sm, float v){
  #pragma unroll
  for (int off = 32; off > 0; off >>= 1) v = fmaxf(v, __shfl_down(v, off, 64));
  __syncthreads();
  if ((threadIdx.x & 63) == 0) sm.red[threadIdx.x >> 6] = v;
  __syncthreads();
  return fmaxf(fmaxf(sm.red[0], sm.red[1]), fmaxf(sm.red[2], sm.red[3]));
}

// argmax with JAX tie rule: first (lowest index) max wins
__device__ __forceinline__ int blockArgMax(SM& sm, float v, int idx){
  #pragma unroll
  for (int off = 32; off > 0; off >>= 1){
    float ov = __shfl_down(v,  off, 64);
    int   oi = __shfl_down(idx, off, 64);
    if (ov > v || (ov == v && oi < idx)){ v = ov; idx = oi; }
  }
  __syncthreads();
  if ((threadIdx.x & 63) == 0){ sm.red[threadIdx.x >> 6] = v; sm.redi[threadIdx.x >> 6] = idx; }
  __syncthreads();
  float bv = sm.red[0]; int bi = sm.redi[0];
  #pragma unroll
  for (int w = 1; w < 4; w++){
    float wv = sm.red[w]; int wi = sm.redi[w];
    if (wv > bv || (wv == bv && wi < bi)){ bv = wv; bi = wi; }
  }
  return bi;   // every thread computes identical result
}

// top-64 membership via rank: rank = #{i: v_i > v_j} + #{i<j: v_i == v_j}; selected iff rank < 64.
__device__ __forceinline__ int rankTop64(SM& sm, float myv){
  int tid = threadIdx.x;
  int cnt = 0;
  const float4* q4 = (const float4*)sm.hsq;
  #pragma unroll 8
  for (int i4 = 0; i4 < 64; i4++){
    float4 o = q4[i4];
    int ib = i4 * 4;
    cnt += (o.x > myv || (o.x == myv && (ib + 0) < tid)) ? 1 : 0;
    cnt += (o.y > myv || (o.y == myv && (ib + 1) < tid)) ? 1 : 0;
    cnt += (o.z > myv || (o.z == myv && (ib + 2) < tid)) ? 1 : 0;
    cnt += (o.w > myv || (o.w == myv && (ib + 3) < tid)) ? 1 : 0;
  }
  return (cnt < 64) ? 1 : 0;
}

// sim_argmax: cosine sim over all 159 shifts of src vs yres; returns theta, fills yal = best window.
__device__ __forceinline__ int simArgmax(SM& sm, const float* src, float* yal_out){
  int tid = threadIdx.x;
  __syncthreads();
  if (tid < 238) sm.spad[tid] = (tid >= 79 && tid < 159) ? src[tid - 79] : 0.f;
  __syncthreads();
  float yv = (tid < 80) ? sm.yres[tid] : 0.f;
  float ny  = blockSum(sm, yv * yv);
  float nys = sqrtf(ny);
  float simv = -INFINITY;
  if (tid < 159){
    float num = 0.f, nx = 0.f;
    const float4* y4 = (const float4*)sm.yres;   // 16B aligned
    #pragma unroll 5
    for (int w4 = 0; w4 < 20; w4++){
      float4 yy = y4[w4];
      int w = w4 * 4;
      float xa0 = sm.spad[tid + w + 0];
      float xa1 = sm.spad[tid + w + 1];
      float xa2 = sm.spad[tid + w + 2];
      float xa3 = sm.spad[tid + w + 3];
      num = fmaf(xa0, yy.x, num); nx = fmaf(xa0, xa0, nx);
      num = fmaf(xa1, yy.y, num); nx = fmaf(xa1, xa1, nx);
      num = fmaf(xa2, yy.z, num); nx = fmaf(xa2, xa2, nx);
      num = fmaf(xa3, yy.w, num); nx = fmaf(xa3, xa3, nx);
    }
    simv = num / (sqrtf(nx) * nys + 1e-6f);
  }
  int th = blockArgMax(sm, simv, tid);
  if (tid < 80) yal_out[tid] = sm.spad[th + tid];
  __syncthreads();
  return th;
}

// Encoder energies via split-precision bf16 MFMA: H = A*We (M=96 padded, N=256, K=160),
// A[s,w] = xp[s+w]. H ~ Ah*Bh + Al*Bh + Ah*Bl (error ~2^-17 rel — argmax-safe).
// M is processed in TWO passes of 48 (3 m-tiles) so the accumulator live set stays
// at 48 VGPRs — the R3 single-pass acc[6][4] (96 VGPRs) spilled to scratch (2.4 GB
// WRITE_SIZE). B fragments are re-read per pass (L2-resident).
// Selected row recomputed exactly in fp32 afterwards, so downstream numerics are unchanged.
__device__ __forceinline__ void branchCompute(
    SM& sm, const float* __restrict__ We, float bej,
    const short8* __restrict__ wsBh, const short8* __restrict__ wsBl, int use_ws,
    const float* __restrict__ Wdec, const float* __restrict__ bdec,
    const float* enc_in, float* mask, const float* target,
    float* dec_out, int theta, bool first, float& lossAcc)
{
  int tid = threadIdx.x;
  int lane = tid & 63, wave = tid >> 6;
  int quad = lane >> 4, l15 = lane & 15;
  __syncthreads();
  // stage xp (float, exact) and xhl (packed bf16 hi|lo, zero outside [80,160))
  {
    float v = (tid >= 80 && tid < 160) ? enc_in[tid - 80] : 0.f;
    if (tid < 240) sm.xp[tid] = v;
    unsigned bits = __float_as_uint(v);
    unsigned hi = bits >> 16;
    float hif = __uint_as_float(hi << 16);
    unsigned lo = __float_as_uint(v - hif) >> 16;
    sm.xhl[tid] = hi | (lo << 16);
  }
  __syncthreads();

  const floatx4 zero4 = {0.f, 0.f, 0.f, 0.f};

  #pragma unroll
  for (int mh = 0; mh < 2; mh++){
    floatx4 acc[3][4];
    #pragma unroll
    for (int m3 = 0; m3 < 3; m3++)
      #pragma unroll
      for (int nt = 0; nt < 4; nt++) acc[m3][nt] = zero4;

    #pragma unroll
    for (int kt = 0; kt < 5; kt++){
      // B fragments for this wave's 4 n-tiles (hi+lo)
      short8 Bh[4], Bl[4];
      #pragma unroll
      for (int nt = 0; nt < 4; nt++){
        int tileIdx = kt * 16 + (wave * 4 + nt);
        if (use_ws){
          Bh[nt] = wsBh[tileIdx * 64 + lane];
          Bl[nt] = wsBl[tileIdx * 64 + lane];
        } else {
          short8 bh, bl;
          int k0 = kt * 32 + quad * 8;
          int n  = (wave * 4 + nt) * 16 + l15;
          #pragma unroll
          for (int j = 0; j < 8; j++){
            float v = We[(k0 + j) * 256 + n];
            unsigned bits = __float_as_uint(v);
            unsigned hi = bits >> 16;
            float hif = __uint_as_float(hi << 16);
            unsigned lo = __float_as_uint(v - hif) >> 16;
            bh[j] = (short)hi; bl[j] = (short)lo;
          }
          Bh[nt] = bh; Bl[nt] = bl;
        }
      }
      short8 Ah[3], Al[3];
      #pragma unroll
      for (int m3 = 0; m3 < 3; m3++){
        int mt = mh * 3 + m3;
        int base = mt * 16 + l15 + kt * 32 + quad * 8;
        short8 ah, al;
        #pragma unroll
        for (int j = 0; j < 8; j++){
          unsigned u = sm.xhl[base + j];
          ah[j] = (short)(u & 0xffffu);
          al[j] = (short)(u >> 16);
        }
        Ah[m3] = ah; Al[m3] = al;
      }
      #pragma unroll
      for (int m3 = 0; m3 < 3; m3++)
        #pragma unroll
        for (int nt = 0; nt < 4; nt++){
          acc[m3][nt] = __builtin_amdgcn_mfma_f32_16x16x32_bf16(Ah[m3], Bh[nt], acc[m3][nt], 0, 0, 0);
          acc[m3][nt] = __builtin_amdgcn_mfma_f32_16x16x32_bf16(Al[m3], Bh[nt], acc[m3][nt], 0, 0, 0);
          acc[m3][nt] = __builtin_amdgcn_mfma_f32_16x16x32_bf16(Ah[m3], Bl[nt], acc[m3][nt], 0, 0, 0);
        }
    }

    // epilogue for this half: add bias, square, reduce over this wave's 64 columns
    float bn[4];
    #pragma unroll
    for (int nt = 0; nt < 4; nt++) bn[nt] = sm.beL[(wave * 4 + nt) * 16 + l15];
    #pragma unroll
    for (int m3 = 0; m3 < 3; m3++){
      int mt = mh * 3 + m3;
      float er[4];
      #pragma unroll
      for (int r = 0; r < 4; r++){
        float s_ = 0.f;
        #pragma unroll
        for (int nt = 0; nt < 4; nt++){
          float hvv = acc[m3][nt][r] + bn[nt];
          s_ = fmaf(hvv, hvv, s_);
        }
        er[r] = s_;
      }
      #pragma unroll
      for (int m2 = 1; m2 < 16; m2 <<= 1){
        #pragma unroll
        for (int r = 0; r < 4; r++) er[r] += __shfl_xor(er[r], m2, 64);
      }
      if (l15 == 0){
        #pragma unroll
        for (int r = 0; r < 4; r++)
          sm.epart4[wave * 96 + mt * 16 + quad * 4 + r] = er[r];
      }
    }
  }
  __syncthreads();
  if (tid < 96)
    sm.energy[tid] = sm.epart4[tid] + sm.epart4[96 + tid] + sm.epart4[192 + tid] + sm.epart4[288 + tid];
  __syncthreads();

  float ev = (tid < 81) ? sm.energy[tid] : -INFINITY;
  int ind = blockArgMax(sm, ev, tid);

  // recompute selected row h[ind, j] EXACTLY in fp32; nonzero support is exactly 80 terms
  const float* wep = We + tid;
  float hv = bej;
  {
    int roff = 80 - ind;   // We row for w2=0
    #pragma unroll 4
    for (int w2 = 0; w2 < 80; w2++)
      hv = fmaf(sm.xp[80 + w2], wep[(w2 + roff) * 256], hv);
  }

  // hsr
  sm.hsq[tid] = hv * hv;
  __syncthreads();
  int sel1 = rankTop64(sm, hv * hv);
  float mpv = mask[tid];
  if (first){
    mask[tid] = (float)sel1;
    sm.hsel[tid] = sel1 ? hv : 0.f;
  } else {
    float interv = mpv * (float)sel1;
    if (interv > 0.f && !sm.smask_t){
      float dd = hv - (1.f - interv);
      lossAcc += dd * dd;
    }
    float h2 = (mpv > 0.f) ? 0.f : hv;
    __syncthreads();               // rank1 readers done before hsq rewrite
    sm.hsq[tid] = h2 * h2;
    __syncthreads();
    int sel2 = rankTop64(sm, h2 * h2);
    mask[tid] = mpv + (float)sel2;
    sm.hsel[tid] = sel2 ? h2 : 0.f;
  }
  __syncthreads();                 // hsel ready

  // decode: ext[d] = bdec[d] + sum_h hsel[h]*Wdec[h*160+d]
  if (tid < 160){
    float a = bdec[tid];
    const float4* h4 = (const float4*)sm.hsel;
    #pragma unroll 4
    for (int hi = 0; hi < 64; hi++){
      float4 hh = h4[hi];
      int hb = hi * 4;
      a = fmaf(hh.x, Wdec[(hb + 0) * 160 + tid], a);
      a = fmaf(hh.y, Wdec[(hb + 1) * 160 + tid], a);
      a = fmaf(hh.z, Wdec[(hb + 2) * 160 + tid], a);
      a = fmaf(hh.w, Wdec[(hb + 3) * 160 + tid], a);
    }
    sm.ext[tid] = a;
  }
  __syncthreads();

  float mv = fabsf((float)(theta - 79));
  bool gate = (mv > 40.0f);        // ETH
  if (tid < 80){
    float dec = sm.ext[ind + tid];
    dec_out[tid] = dec;            // residual update uses decoded output regardless of gates
    float diff = dec - target[tid];
    float l = (gate || sm.smask[tid]) ? 0.f : diff * diff;
    lossAcc += l / (mv + 1.0f);
  }
  __syncthreads();
}

__global__ void __launch_bounds__(64) zero_out_kernel(float* out){
  if (threadIdx.x == 0) out[0] = 0.f;
}

// Pre-repack We into MFMA B-fragment layout (bf16 hi and lo), one 16B frag per lane per tile.
// grid: 80 blocks = kt(5) x nt(16); 64 threads.
__global__ void __launch_bounds__(64) prep_we_kernel(
    const float* __restrict__ We, short8* __restrict__ bh, short8* __restrict__ bl){
  int tile = blockIdx.x;
  int lane = threadIdx.x;
  int kt = tile >> 4, nt = tile & 15;
  int k0 = kt * 32 + (lane >> 4) * 8;
  int n  = nt * 16 + (lane & 15);
  short8 h, l;
  #pragma unroll
  for (int j = 0; j < 8; j++){
    float v = We[(k0 + j) * 256 + n];
    unsigned bits = __float_as_uint(v);
    unsigned hi = bits >> 16;
    float hif = __uint_as_float(hi << 16);
    unsigned lo = __float_as_uint(v - hif) >> 16;
    h[j] = (short)hi; l[j] = (short)lo;
  }
  bh[tile * 64 + lane] = h;
  bl[tile * 64 + lane] = l;
}

__global__ void __launch_bounds__(256) net_kernel(
    const float* __restrict__ x,  const float* __restrict__ y,
    const float* __restrict__ We, const float* __restrict__ be,
    const float* __restrict__ Wd, const float* __restrict__ bd,
    const float* __restrict__ Wds,const float* __restrict__ bds,
    const short8* __restrict__ wsBh, const short8* __restrict__ wsBl, int use_ws,
    float* out)
{
  __shared__ SM sm;
  int tid = threadIdx.x;
  int bt  = blockIdx.x;
  const float* xin = x + bt * 80;
  const float* yin = y + bt * 80;

  if (tid < 80){
    sm.xres[tid] = xin[tid];
    float yv = yin[tid];
    sm.yres[tid] = yv;
    sm.smask[tid] = (yv == 0.f) ? 1 : 0;   // seq_mask from ORIGINAL y
  }
  sm.mp_self[tid] = 0.f;
  sm.mp_src[tid]  = 0.f;
  float bej = be[tid];
  sm.beL[tid] = bej;
  __syncthreads();
  if (tid == 0){
    int a = 1;
    for (int i = 0; i < 80; i++) a &= (int)sm.smask[i];
    sm.smask_t = a;
  }
  __syncthreads();

  float lossAcc = 0.f;

  for (int it = 0; it < 4; it++){
    bool first = (it == 0);

    // --- align x_res to y_res ---
    int th1 = simArgmax(sm, sm.xres, sm.yal);

    // --- attention softmax(y_al * y_res) and z = y_al * attn ---
    float pv = (tid < 80) ? sm.yal[tid] * sm.yres[tid] : -INFINITY;
    float mx = blockMax(sm, pv);
    float e  = (tid < 80) ? expf(pv - mx) : 0.f;
    float ssum = blockSum(sm, e);
    if (tid < 80) sm.zb[tid] = sm.yal[tid] * (e / ssum);
    __syncthreads();

    // --- reverse shift: x_ele[d] = z[d + 79 - theta] ---
    if (tid < 80){
      int q = tid + 79 - th1;
      sm.xele[tid] = (q >= 0 && q < 80) ? sm.zb[q] : 0.f;
    }

    // --- self branch ---
    branchCompute(sm, We, bej, wsBh, wsBl, use_ws, Wds, bds,
                  sm.xele, sm.mp_self, sm.xres, sm.xele, th1, first, lossAcc);

    // --- re-align decoded x_ele to y_res ---
    int th2 = simArgmax(sm, sm.xele, sm.yal);

    // --- src branch ---
    branchCompute(sm, We, bej, wsBh, wsBl, use_ws, Wd, bd,
                  sm.yal, sm.mp_src, sm.yres, sm.decsrc, th2, first, lossAcc);

    // --- residual updates ---
    __syncthreads();
    if (tid < 80){
      sm.xres[tid] -= sm.xele[tid];
      sm.yres[tid] -= sm.decsrc[tid];
    }
    __syncthreads();
  }

  float total = blockSum(sm, lossAcc);
  if (tid == 0) atomicAdd(out, total * 0.25f);   // mean over 4 iterations
}

extern "C" void kernel_launch(void* const* d_in, const int* in_sizes, int n_in,
                              void* d_out, int out_size, void* d_ws, size_t ws_size,
                              hipStream_t stream) {
  const float* x   = (const float*)d_in[0];
  const float* y   = (const float*)d_in[1];
  const float* We  = (const float*)d_in[2];
  const float* be  = (const float*)d_in[3];
  const float* Wd  = (const float*)d_in[4];
  const float* bd  = (const float*)d_in[5];
  const float* Wds = (const float*)d_in[6];
  const float* bds = (const float*)d_in[7];
  float* out = (float*)d_out;

  // We-fragment repack buffers: 80 tiles x 64 lanes x 16B each for hi and lo
  const size_t fragCount = 80 * 64;                 // short8 elements per buffer
  const size_t fragBytes = fragCount * sizeof(short8);  // 81920 B
  int use_ws = (ws_size >= 2 * fragBytes) ? 1 : 0;
  short8* wsBh = (short8*)d_ws;
  short8* wsBl = wsBh + fragCount;

  hipLaunchKernelGGL(zero_out_kernel, dim3(1), dim3(64), 0, stream, out);
  if (use_ws)
    hipLaunchKernelGGL(prep_we_kernel, dim3(80), dim3(64), 0, stream, We, wsBh, wsBl);
  hipLaunchKernelGGL(net_kernel, dim3(NBT), dim3(256), 0, stream,
                     x, y, We, be, Wd, bd, Wds, bds, wsBh, wsBl, use_ws, out);
}

// Round 5
// 1593.648 us; speedup vs baseline: 2.3523x; 2.3523x over previous
//
#include <hip/hip_runtime.h>
#include <math.h>

// Problem constants (B=8, T=256 -> 2048 independent (b,t) pipelines)
#define NBT 2048

typedef __attribute__((ext_vector_type(8))) short short8;     // 8 bf16 (4 VGPRs)
typedef __attribute__((ext_vector_type(4))) float floatx4;    // MFMA C/D

struct SM {
  alignas(16) float xp[240];      // zero-padded encoder input (nonzero in [80,160))
  alignas(16) unsigned xhl[256];  // packed bf16: hi | lo<<16, zero-padded to 256
  alignas(16) float hsq[256];     // h^2 for top-64 ranking
  alignas(16) float hsel[256];    // masked hidden vector (decode input)
  alignas(16) float yres[80];
  alignas(16) float beL[256];     // encoder bias staged in LDS
  float xres[80];
  float yal[80];
  float xele[80];
  float decsrc[80];
  float zb[80];
  float spad[238];                // padded buffer for sim windows
  float energy[96];               // 81 valid + pad to 96 (6 m-tiles of 16)
  float epart4[384];              // 4 waves x 96 rows of per-wave energy partials
  float mp_self[256];
  float mp_src[256];
  float ext[160];
  float red[4];
  int   redi[4];
  unsigned char smask[80];
  int smask_t;
};

__device__ __forceinline__ float warpSum(float v){
  #pragma unroll
  for (int off = 32; off > 0; off >>= 1) v += __shfl_down(v, off, 64);
  return v;
}

__device__ __forceinline__ float blockSum(SM& sm, float v){
  v = warpSum(v);
  int wave = threadIdx.x >> 6;
  __syncthreads();                     // protect red[] from previous use
  if ((threadIdx.x & 63) == 0) sm.red[wave] = v;
  __syncthreads();
  return sm.red[0] + sm.red[1] + sm.red[2] + sm.red[3];
}

__device__ __forceinline__ float blockMax(SM& sm, float v){
  #pragma unroll
  for (int off = 32; off > 0; off >>= 1) v = fmaxf(v, __shfl_down(v, off, 64));
  __syncthreads();
  if ((threadIdx.x & 63) == 0) sm.red[threadIdx.x >> 6] = v;
  __syncthreads();
  return fmaxf(fmaxf(sm.red[0], sm.red[1]), fmaxf(sm.red[2], sm.red[3]));
}

// argmax with JAX tie rule: first (lowest index) max wins
__device__ __forceinline__ int blockArgMax(SM& sm, float v, int idx){
  #pragma unroll
  for (int off = 32; off > 0; off >>= 1){
    float ov = __shfl_down(v,  off, 64);
    int   oi = __shfl_down(idx, off, 64);
    if (ov > v || (ov == v && oi < idx)){ v = ov; idx = oi; }
  }
  __syncthreads();
  if ((threadIdx.x & 63) == 0){ sm.red[threadIdx.x >> 6] = v; sm.redi[threadIdx.x >> 6] = idx; }
  __syncthreads();
  float bv = sm.red[0]; int bi = sm.redi[0];
  #pragma unroll
  for (int w = 1; w < 4; w++){
    float wv = sm.red[w]; int wi = sm.redi[w];
    if (wv > bv || (wv == bv && wi < bi)){ bv = wv; bi = wi; }
  }
  return bi;   // every thread computes identical result
}

// top-64 membership via rank: rank = #{i: v_i > v_j} + #{i<j: v_i == v_j}; selected iff rank < 64.
__device__ __forceinline__ int rankTop64(SM& sm, float myv){
  int tid = threadIdx.x;
  int cnt = 0;
  const float4* q4 = (const float4*)sm.hsq;
  #pragma unroll 8
  for (int i4 = 0; i4 < 64; i4++){
    float4 o = q4[i4];
    int ib = i4 * 4;
    cnt += (o.x > myv || (o.x == myv && (ib + 0) < tid)) ? 1 : 0;
    cnt += (o.y > myv || (o.y == myv && (ib + 1) < tid)) ? 1 : 0;
    cnt += (o.z > myv || (o.z == myv && (ib + 2) < tid)) ? 1 : 0;
    cnt += (o.w > myv || (o.w == myv && (ib + 3) < tid)) ? 1 : 0;
  }
  return (cnt < 64) ? 1 : 0;
}

// sim_argmax: cosine sim over all 159 shifts of src vs yres; returns theta, fills yal = best window.
__device__ __forceinline__ int simArgmax(SM& sm, const float* src, float* yal_out){
  int tid = threadIdx.x;
  __syncthreads();
  if (tid < 238) sm.spad[tid] = (tid >= 79 && tid < 159) ? src[tid - 79] : 0.f;
  __syncthreads();
  float yv = (tid < 80) ? sm.yres[tid] : 0.f;
  float ny  = blockSum(sm, yv * yv);
  float nys = sqrtf(ny);
  float simv = -INFINITY;
  if (tid < 159){
    float num = 0.f, nx = 0.f;
    const float4* y4 = (const float4*)sm.yres;   // 16B aligned
    #pragma unroll 5
    for (int w4 = 0; w4 < 20; w4++){
      float4 yy = y4[w4];
      int w = w4 * 4;
      float xa0 = sm.spad[tid + w + 0];
      float xa1 = sm.spad[tid + w + 1];
      float xa2 = sm.spad[tid + w + 2];
      float xa3 = sm.spad[tid + w + 3];
      num = fmaf(xa0, yy.x, num); nx = fmaf(xa0, xa0, nx);
      num = fmaf(xa1, yy.y, num); nx = fmaf(xa1, xa1, nx);
      num = fmaf(xa2, yy.z, num); nx = fmaf(xa2, xa2, nx);
      num = fmaf(xa3, yy.w, num); nx = fmaf(xa3, xa3, nx);
    }
    simv = num / (sqrtf(nx) * nys + 1e-6f);
  }
  int th = blockArgMax(sm, simv, tid);
  if (tid < 80) yal_out[tid] = sm.spad[th + tid];
  __syncthreads();
  return th;
}

// Encoder energies via split-precision bf16 MFMA: H = A*We (M=96 padded, N=256, K=160),
// A[s,w] = xp[s+w]. H ~ Ah*Bh + Al*Bh + Ah*Bl (error ~2^-17 rel — argmax-safe; absmax=0
// in R3/R4). M processed in THREE passes of 2 m-tiles with `#pragma unroll 1` + barrier
// so the compiler CANNOT merge passes (R3: 96-acc spilled; R4: unrolled passes re-merged
// -> 256 VGPR + 280 MB scratch). Live set per pass: acc 32 + B 32 + A 16 ~= 80 VGPRs.
// Selected row recomputed exactly in fp32 afterwards, so downstream numerics are unchanged.
template<int USE_WS>
__device__ __forceinline__ void branchCompute(
    SM& sm, const float* __restrict__ We, float bej,
    const short8* __restrict__ wsBh, const short8* __restrict__ wsBl,
    const float* __restrict__ Wdec, const float* __restrict__ bdec,
    const float* enc_in, float* mask, const float* target,
    float* dec_out, int theta, bool first, float& lossAcc)
{
  int tid = threadIdx.x;
  int lane = tid & 63, wave = tid >> 6;
  int quad = lane >> 4, l15 = lane & 15;
  __syncthreads();
  // stage xp (float, exact) and xhl (packed bf16 hi|lo, zero outside [80,160))
  {
    float v = (tid >= 80 && tid < 160) ? enc_in[tid - 80] : 0.f;
    if (tid < 240) sm.xp[tid] = v;
    unsigned bits = __float_as_uint(v);
    unsigned hi = bits >> 16;
    float hif = __uint_as_float(hi << 16);
    unsigned lo = __float_as_uint(v - hif) >> 16;
    sm.xhl[tid] = hi | (lo << 16);
  }
  __syncthreads();

  const floatx4 zero4 = {0.f, 0.f, 0.f, 0.f};

  #pragma unroll 1
  for (int mh = 0; mh < 3; mh++){      // 3 passes x 2 m-tiles; NOT unrolled (spill guard)
    floatx4 acc[2][4];
    #pragma unroll
    for (int m2 = 0; m2 < 2; m2++)
      #pragma unroll
      for (int nt = 0; nt < 4; nt++) acc[m2][nt] = zero4;

    #pragma unroll
    for (int kt = 0; kt < 5; kt++){
      // B fragments for this wave's 4 n-tiles (hi+lo)
      short8 Bh[4], Bl[4];
      #pragma unroll
      for (int nt = 0; nt < 4; nt++){
        int tileIdx = kt * 16 + (wave * 4 + nt);
        if (USE_WS){
          Bh[nt] = wsBh[tileIdx * 64 + lane];
          Bl[nt] = wsBl[tileIdx * 64 + lane];
        } else {
          short8 bh, bl;
          int k0 = kt * 32 + quad * 8;
          int n  = (wave * 4 + nt) * 16 + l15;
          #pragma unroll
          for (int j = 0; j < 8; j++){
            float v = We[(k0 + j) * 256 + n];
            unsigned bits = __float_as_uint(v);
            unsigned hi = bits >> 16;
            float hif = __uint_as_float(hi << 16);
            unsigned lo = __float_as_uint(v - hif) >> 16;
            bh[j] = (short)hi; bl[j] = (short)lo;
          }
          Bh[nt] = bh; Bl[nt] = bl;
        }
      }
      short8 Ah[2], Al[2];
      #pragma unroll
      for (int m2 = 0; m2 < 2; m2++){
        int mt = mh * 2 + m2;
        int base = mt * 16 + l15 + kt * 32 + quad * 8;
        short8 ah, al;
        #pragma unroll
        for (int j = 0; j < 8; j++){
          unsigned u = sm.xhl[base + j];
          ah[j] = (short)(u & 0xffffu);
          al[j] = (short)(u >> 16);
        }
        Ah[m2] = ah; Al[m2] = al;
      }
      #pragma unroll
      for (int m2 = 0; m2 < 2; m2++)
        #pragma unroll
        for (int nt = 0; nt < 4; nt++){
          acc[m2][nt] = __builtin_amdgcn_mfma_f32_16x16x32_bf16(Ah[m2], Bh[nt], acc[m2][nt], 0, 0, 0);
          acc[m2][nt] = __builtin_amdgcn_mfma_f32_16x16x32_bf16(Al[m2], Bh[nt], acc[m2][nt], 0, 0, 0);
          acc[m2][nt] = __builtin_amdgcn_mfma_f32_16x16x32_bf16(Ah[m2], Bl[nt], acc[m2][nt], 0, 0, 0);
        }
    }

    // epilogue for this pass: add bias, square, reduce over this wave's 64 columns
    float bn[4];
    #pragma unroll
    for (int nt = 0; nt < 4; nt++) bn[nt] = sm.beL[(wave * 4 + nt) * 16 + l15];
    #pragma unroll
    for (int m2 = 0; m2 < 2; m2++){
      int mt = mh * 2 + m2;
      float er[4];
      #pragma unroll
      for (int r = 0; r < 4; r++){
        float s_ = 0.f;
        #pragma unroll
        for (int nt = 0; nt < 4; nt++){
          float hvv = acc[m2][nt][r] + bn[nt];
          s_ = fmaf(hvv, hvv, s_);
        }
        er[r] = s_;
      }
      #pragma unroll
      for (int x2 = 1; x2 < 16; x2 <<= 1){
        #pragma unroll
        for (int r = 0; r < 4; r++) er[r] += __shfl_xor(er[r], x2, 64);
      }
      if (l15 == 0){
        #pragma unroll
        for (int r = 0; r < 4; r++)
          sm.epart4[wave * 96 + mt * 16 + quad * 4 + r] = er[r];
      }
    }
    __syncthreads();   // hard fence: keeps passes physically sequential (spill guard)
  }
  if (tid < 96)
    sm.energy[tid] = sm.epart4[tid] + sm.epart4[96 + tid] + sm.epart4[192 + tid] + sm.epart4[288 + tid];
  __syncthreads();

  float ev = (tid < 81) ? sm.energy[tid] : -INFINITY;
  int ind = blockArgMax(sm, ev, tid);

  // recompute selected row h[ind, j] EXACTLY in fp32; nonzero support is exactly 80 terms
  const float* wep = We + tid;
  float hv = bej;
  {
    int roff = 80 - ind;   // We row for w2=0
    #pragma unroll 4
    for (int w2 = 0; w2 < 80; w2++)
      hv = fmaf(sm.xp[80 + w2], wep[(w2 + roff) * 256], hv);
  }

  // hsr
  sm.hsq[tid] = hv * hv;
  __syncthreads();
  int sel1 = rankTop64(sm, hv * hv);
  float mpv = mask[tid];
  if (first){
    mask[tid] = (float)sel1;
    sm.hsel[tid] = sel1 ? hv : 0.f;
  } else {
    float interv = mpv * (float)sel1;
    if (interv > 0.f && !sm.smask_t){
      float dd = hv - (1.f - interv);
      lossAcc += dd * dd;
    }
    float h2 = (mpv > 0.f) ? 0.f : hv;
    __syncthreads();               // rank1 readers done before hsq rewrite
    sm.hsq[tid] = h2 * h2;
    __syncthreads();
    int sel2 = rankTop64(sm, h2 * h2);
    mask[tid] = mpv + (float)sel2;
    sm.hsel[tid] = sel2 ? h2 : 0.f;
  }
  __syncthreads();                 // hsel ready

  // decode: ext[d] = bdec[d] + sum_h hsel[h]*Wdec[h*160+d]
  if (tid < 160){
    float a = bdec[tid];
    const float4* h4 = (const float4*)sm.hsel;
    #pragma unroll 4
    for (int hi = 0; hi < 64; hi++){
      float4 hh = h4[hi];
      int hb = hi * 4;
      a = fmaf(hh.x, Wdec[(hb + 0) * 160 + tid], a);
      a = fmaf(hh.y, Wdec[(hb + 1) * 160 + tid], a);
      a = fmaf(hh.z, Wdec[(hb + 2) * 160 + tid], a);
      a = fmaf(hh.w, Wdec[(hb + 3) * 160 + tid], a);
    }
    sm.ext[tid] = a;
  }
  __syncthreads();

  float mv = fabsf((float)(theta - 79));
  bool gate = (mv > 40.0f);        // ETH
  if (tid < 80){
    float dec = sm.ext[ind + tid];
    dec_out[tid] = dec;            // residual update uses decoded output regardless of gates
    float diff = dec - target[tid];
    float l = (gate || sm.smask[tid]) ? 0.f : diff * diff;
    lossAcc += l / (mv + 1.0f);
  }
  __syncthreads();
}

__global__ void __launch_bounds__(64) zero_out_kernel(float* out){
  if (threadIdx.x == 0) out[0] = 0.f;
}

// Pre-repack We into MFMA B-fragment layout (bf16 hi and lo), one 16B frag per lane per tile.
// grid: 80 blocks = kt(5) x nt(16); 64 threads.
__global__ void __launch_bounds__(64) prep_we_kernel(
    const float* __restrict__ We, short8* __restrict__ bh, short8* __restrict__ bl){
  int tile = blockIdx.x;
  int lane = threadIdx.x;
  int kt = tile >> 4, nt = tile & 15;
  int k0 = kt * 32 + (lane >> 4) * 8;
  int n  = nt * 16 + (lane & 15);
  short8 h, l;
  #pragma unroll
  for (int j = 0; j < 8; j++){
    float v = We[(k0 + j) * 256 + n];
    unsigned bits = __float_as_uint(v);
    unsigned hi = bits >> 16;
    float hif = __uint_as_float(hi << 16);
    unsigned lo = __float_as_uint(v - hif) >> 16;
    h[j] = (short)hi; l[j] = (short)lo;
  }
  bh[tile * 64 + lane] = h;
  bl[tile * 64 + lane] = l;
}

template<int USE_WS>
__global__ void __launch_bounds__(256) net_kernel(
    const float* __restrict__ x,  const float* __restrict__ y,
    const float* __restrict__ We, const float* __restrict__ be,
    const float* __restrict__ Wd, const float* __restrict__ bd,
    const float* __restrict__ Wds,const float* __restrict__ bds,
    const short8* __restrict__ wsBh, const short8* __restrict__ wsBl,
    float* out)
{
  __shared__ SM sm;
  int tid = threadIdx.x;
  int bt  = blockIdx.x;
  const float* xin = x + bt * 80;
  const float* yin = y + bt * 80;

  if (tid < 80){
    sm.xres[tid] = xin[tid];
    float yv = yin[tid];
    sm.yres[tid] = yv;
    sm.smask[tid] = (yv == 0.f) ? 1 : 0;   // seq_mask from ORIGINAL y
  }
  sm.mp_self[tid] = 0.f;
  sm.mp_src[tid]  = 0.f;
  float bej = be[tid];
  sm.beL[tid] = bej;
  __syncthreads();
  if (tid == 0){
    int a = 1;
    for (int i = 0; i < 80; i++) a &= (int)sm.smask[i];
    sm.smask_t = a;
  }
  __syncthreads();

  float lossAcc = 0.f;

  for (int it = 0; it < 4; it++){
    bool first = (it == 0);

    // --- align x_res to y_res ---
    int th1 = simArgmax(sm, sm.xres, sm.yal);

    // --- attention softmax(y_al * y_res) and z = y_al * attn ---
    float pv = (tid < 80) ? sm.yal[tid] * sm.yres[tid] : -INFINITY;
    float mx = blockMax(sm, pv);
    float e  = (tid < 80) ? expf(pv - mx) : 0.f;
    float ssum = blockSum(sm, e);
    if (tid < 80) sm.zb[tid] = sm.yal[tid] * (e / ssum);
    __syncthreads();

    // --- reverse shift: x_ele[d] = z[d + 79 - theta] ---
    if (tid < 80){
      int q = tid + 79 - th1;
      sm.xele[tid] = (q >= 0 && q < 80) ? sm.zb[q] : 0.f;
    }

    // --- self branch ---
    branchCompute<USE_WS>(sm, We, bej, wsBh, wsBl, Wds, bds,
                          sm.xele, sm.mp_self, sm.xres, sm.xele, th1, first, lossAcc);

    // --- re-align decoded x_ele to y_res ---
    int th2 = simArgmax(sm, sm.xele, sm.yal);

    // --- src branch ---
    branchCompute<USE_WS>(sm, We, bej, wsBh, wsBl, Wd, bd,
                          sm.yal, sm.mp_src, sm.yres, sm.decsrc, th2, first, lossAcc);

    // --- residual updates ---
    __syncthreads();
    if (tid < 80){
      sm.xres[tid] -= sm.xele[tid];
      sm.yres[tid] -= sm.decsrc[tid];
    }
    __syncthreads();
  }

  float total = blockSum(sm, lossAcc);
  if (tid == 0) atomicAdd(out, total * 0.25f);   // mean over 4 iterations
}

extern "C" void kernel_launch(void* const* d_in, const int* in_sizes, int n_in,
                              void* d_out, int out_size, void* d_ws, size_t ws_size,
                              hipStream_t stream) {
  const float* x   = (const float*)d_in[0];
  const float* y   = (const float*)d_in[1];
  const float* We  = (const float*)d_in[2];
  const float* be  = (const float*)d_in[3];
  const float* Wd  = (const float*)d_in[4];
  const float* bd  = (const float*)d_in[5];
  const float* Wds = (const float*)d_in[6];
  const float* bds = (const float*)d_in[7];
  float* out = (float*)d_out;

  // We-fragment repack buffers: 80 tiles x 64 lanes x 16B each for hi and lo
  const size_t fragCount = 80 * 64;                     // short8 elements per buffer
  const size_t fragBytes = fragCount * sizeof(short8);  // 81920 B
  int use_ws = (ws_size >= 2 * fragBytes) ? 1 : 0;
  short8* wsBh = (short8*)d_ws;
  short8* wsBl = wsBh + fragCount;

  hipLaunchKernelGGL(zero_out_kernel, dim3(1), dim3(64), 0, stream, out);
  if (use_ws){
    hipLaunchKernelGGL(prep_we_kernel, dim3(80), dim3(64), 0, stream, We, wsBh, wsBl);
    hipLaunchKernelGGL((net_kernel<1>), dim3(NBT), dim3(256), 0, stream,
                       x, y, We, be, Wd, bd, Wds, bds, wsBh, wsBl, out);
  } else {
    hipLaunchKernelGGL((net_kernel<0>), dim3(NBT), dim3(256), 0, stream,
                       x, y, We, be, Wd, bd, Wds, bds, wsBh, wsBl, out);
  }
}

// Round 6
// 990.467 us; speedup vs baseline: 3.7848x; 1.6090x over previous
//
#include <hip/hip_runtime.h>
#include <math.h>

// Problem constants (B=8, T=256 -> 2048 independent (b,t) pipelines)
// R6 structure: ONE WAVE (64 threads) per pipeline. No inter-wave barriers exist;
// __syncthreads in a single-wave workgroup lowers to waitcnt only.
#define NBT 2048

typedef __attribute__((ext_vector_type(8))) short short8;     // 8 bf16 (4 VGPRs)
typedef __attribute__((ext_vector_type(4))) float floatx4;    // MFMA C/D

struct SM {
  alignas(16) float xp[240];      // zero-padded encoder input (nonzero in [80,160))
  alignas(16) unsigned xhl[256];  // packed bf16: hi | lo<<16, zero-padded to 256
  alignas(16) float hsq[256];     // h^2 for top-64 ranking
  alignas(16) float hsel[256];    // masked hidden vector (decode input)
  alignas(16) float yres[80];
  alignas(16) float beL[256];     // encoder bias staged in LDS
  alignas(16) float spad[240];    // padded buffer for sim windows
  float xres[80];
  float yal[80];
  float xele[80];
  float decsrc[80];
  float zb[80];
  float energy[96];               // 81 valid + pad (6 m-tiles of 16)
  float mp_self[256];
  float mp_src[256];
  float ext[160];
  unsigned char smask[80];
  int smask_t;
};

// ---- wave-level primitives (64 lanes, butterfly -> all lanes hold result) ----
__device__ __forceinline__ float waveSum(float v){
  #pragma unroll
  for (int off = 32; off > 0; off >>= 1) v += __shfl_xor(v, off, 64);
  return v;
}
__device__ __forceinline__ int waveSumI(int v){
  #pragma unroll
  for (int off = 32; off > 0; off >>= 1) v += __shfl_xor(v, off, 64);
  return v;
}
__device__ __forceinline__ float waveMax(float v){
  #pragma unroll
  for (int off = 32; off > 0; off >>= 1) v = fmaxf(v, __shfl_xor(v, off, 64));
  return v;
}
// argmax with JAX tie rule: first (lowest index) max wins; symmetric butterfly
__device__ __forceinline__ int waveArgMax(float v, int idx){
  #pragma unroll
  for (int off = 32; off > 0; off >>= 1){
    float ov = __shfl_xor(v,   off, 64);
    int   oi = __shfl_xor(idx, off, 64);
    if (ov > v || (ov == v && oi < idx)){ v = ov; idx = oi; }
  }
  return idx;
}

// top-64 membership via rank for this lane's 4 hidden units (j = lane + 64q).
// rank = #{i: v_i > v_j} + #{i<j: v_i == v_j}; selected iff rank < 64.
// hsq[i4] reads are wave-uniform -> LDS broadcast, conflict-free.
__device__ __forceinline__ void rankTop64w(SM& sm, const float vsq[4], int lane, int sel[4]){
  int cnt[4] = {0,0,0,0};
  const float4* q4 = (const float4*)sm.hsq;
  #pragma unroll 4
  for (int i4 = 0; i4 < 64; i4++){
    float4 o = q4[i4];
    int ib = i4 * 4;
    #pragma unroll
    for (int q = 0; q < 4; q++){
      int j = lane + 64 * q;
      cnt[q] += (o.x > vsq[q] || (o.x == vsq[q] && (ib + 0) < j)) ? 1 : 0;
      cnt[q] += (o.y > vsq[q] || (o.y == vsq[q] && (ib + 1) < j)) ? 1 : 0;
      cnt[q] += (o.z > vsq[q] || (o.z == vsq[q] && (ib + 2) < j)) ? 1 : 0;
      cnt[q] += (o.w > vsq[q] || (o.w == vsq[q] && (ib + 3) < j)) ? 1 : 0;
    }
  }
  #pragma unroll
  for (int q = 0; q < 4; q++) sel[q] = (cnt[q] < 64) ? 1 : 0;
}

// sim_argmax: cosine sim over 159 shifts of src vs yres; each lane owns shifts
// {lane, lane+64, lane+128}. Per-candidate fmaf chain order matches R5 exactly.
__device__ __forceinline__ int simArgmax(SM& sm, const float* src, float* yal_out){
  int lane = threadIdx.x;
  __syncthreads();
  for (int i = lane; i < 240; i += 64)
    sm.spad[i] = (i >= 79 && i < 159) ? src[i - 79] : 0.f;
  __syncthreads();
  float yv2 = 0.f;
  for (int w = lane; w < 80; w += 64){ float yv = sm.yres[w]; yv2 = fmaf(yv, yv, yv2); }
  float nys = sqrtf(waveSum(yv2));

  int   sidx[3]; int svalid[3];
  #pragma unroll
  for (int c = 0; c < 3; c++){
    int s = lane + 64 * c;
    svalid[c] = (s < 159);
    sidx[c] = svalid[c] ? s : 0;      // clamp to keep reads in-bounds
  }
  float num[3] = {0.f,0.f,0.f}, nx[3] = {0.f,0.f,0.f};
  const float4* y4p = (const float4*)sm.yres;
  for (int w4 = 0; w4 < 20; w4++){
    float4 yy = y4p[w4];
    int w = w4 * 4;
    #pragma unroll
    for (int c = 0; c < 3; c++){
      float xa0 = sm.spad[sidx[c] + w + 0];
      float xa1 = sm.spad[sidx[c] + w + 1];
      float xa2 = sm.spad[sidx[c] + w + 2];
      float xa3 = sm.spad[sidx[c] + w + 3];
      num[c] = fmaf(xa0, yy.x, num[c]); nx[c] = fmaf(xa0, xa0, nx[c]);
      num[c] = fmaf(xa1, yy.y, num[c]); nx[c] = fmaf(xa1, xa1, nx[c]);
      num[c] = fmaf(xa2, yy.z, num[c]); nx[c] = fmaf(xa2, xa2, nx[c]);
      num[c] = fmaf(xa3, yy.w, num[c]); nx[c] = fmaf(xa3, xa3, nx[c]);
    }
  }
  float bv = -INFINITY; int bi = 0;
  #pragma unroll
  for (int c = 0; c < 3; c++){          // ascending index: strict > keeps lowest idx on ties
    if (svalid[c]){
      float simv = num[c] / (sqrtf(nx[c]) * nys + 1e-6f);
      if (simv > bv){ bv = simv; bi = lane + 64 * c; }
    }
  }
  int th = waveArgMax(bv, bi);
  for (int i = lane; i < 80; i += 64) yal_out[i] = sm.spad[th + i];
  __syncthreads();
  return th;
}

// One branch: MFMA energy (split bf16, kt-trimmed to nonzero support — bit-safe),
// argmax, exact fp32 row recompute, hsr, decode, masked loss.
template<int USE_WS>
__device__ __forceinline__ void branchCompute(
    SM& sm, const float* __restrict__ We,
    const short8* __restrict__ wsBh, const short8* __restrict__ wsBl,
    const float* __restrict__ Wdec, const float* __restrict__ bdec,
    const float* enc_in, float* mask, const float* target,
    float* dec_out, int theta, bool first, float& lossAcc)
{
  int lane = threadIdx.x;
  int quad = lane >> 4, l15 = lane & 15;
  __syncthreads();
  for (int i = lane; i < 256; i += 64){
    float v = (i >= 80 && i < 160) ? enc_in[i - 80] : 0.f;
    if (i < 240) sm.xp[i] = v;
    unsigned bits = __float_as_uint(v);
    unsigned hi = bits >> 16;
    float hif = __uint_as_float(hi << 16);
    unsigned lo = __float_as_uint(v - hif) >> 16;
    sm.xhl[i] = hi | (lo << 16);
  }
  __syncthreads();

  const floatx4 zero4 = {0.f, 0.f, 0.f, 0.f};

  #pragma unroll 1
  for (int mh = 0; mh < 3; mh++){        // 2 m-tiles per pass (acc = 32 VGPR)
    int ktlo = (mh == 0) ? 1 : 0;        // nonzero-support kt range for these m rows
    int kthi = 5 - mh;
    #pragma unroll 1
    for (int ng = 0; ng < 4; ng++){      // 4 n-tiles per pass
      floatx4 acc[2][4];
      #pragma unroll
      for (int m2 = 0; m2 < 2; m2++)
        #pragma unroll
        for (int nt = 0; nt < 4; nt++) acc[m2][nt] = zero4;

      #pragma unroll
      for (int kt = 0; kt < 5; kt++){
        if (kt < ktlo || kt >= kthi) continue;   // wave-uniform scalar skip; removed
                                                 // products are exactly 0 -> bit-safe
        short8 Bh[4], Bl[4];
        #pragma unroll
        for (int nt = 0; nt < 4; nt++){
          int tileIdx = kt * 16 + (ng * 4 + nt);
          if (USE_WS){
            Bh[nt] = wsBh[tileIdx * 64 + lane];
            Bl[nt] = wsBl[tileIdx * 64 + lane];
          } else {
            short8 bh, bl;
            int k0 = kt * 32 + quad * 8;
            int n  = (ng * 4 + nt) * 16 + l15;
            #pragma unroll
            for (int j = 0; j < 8; j++){
              float v = We[(k0 + j) * 256 + n];
              unsigned bits = __float_as_uint(v);
              unsigned hi = bits >> 16;
              float hif = __uint_as_float(hi << 16);
              unsigned lo = __float_as_uint(v - hif) >> 16;
              bh[j] = (short)hi; bl[j] = (short)lo;
            }
            Bh[nt] = bh; Bl[nt] = bl;
          }
        }
        short8 Ah[2], Al[2];
        #pragma unroll
        for (int m2 = 0; m2 < 2; m2++){
          int mt = mh * 2 + m2;
          int base = mt * 16 + l15 + kt * 32 + quad * 8;
          short8 ah, al;
          #pragma unroll
          for (int j = 0; j < 8; j++){
            unsigned u = sm.xhl[base + j];
            ah[j] = (short)(u & 0xffffu);
            al[j] = (short)(u >> 16);
          }
          Ah[m2] = ah; Al[m2] = al;
        }
        #pragma unroll
        for (int m2 = 0; m2 < 2; m2++)
          #pragma unroll
          for (int nt = 0; nt < 4; nt++){
            acc[m2][nt] = __builtin_amdgcn_mfma_f32_16x16x32_bf16(Ah[m2], Bh[nt], acc[m2][nt], 0, 0, 0);
            acc[m2][nt] = __builtin_amdgcn_mfma_f32_16x16x32_bf16(Al[m2], Bh[nt], acc[m2][nt], 0, 0, 0);
            acc[m2][nt] = __builtin_amdgcn_mfma_f32_16x16x32_bf16(Ah[m2], Bl[nt], acc[m2][nt], 0, 0, 0);
          }
      }

      // epilogue: add bias, square, reduce over this pass's 64 columns (l15 butterfly)
      float bn[4];
      #pragma unroll
      for (int nt = 0; nt < 4; nt++) bn[nt] = sm.beL[(ng * 4 + nt) * 16 + l15];
      #pragma unroll
      for (int m2 = 0; m2 < 2; m2++){
        int mt = mh * 2 + m2;
        float er[4];
        #pragma unroll
        for (int r = 0; r < 4; r++){
          float s_ = 0.f;
          #pragma unroll
          for (int nt = 0; nt < 4; nt++){
            float hvv = acc[m2][nt][r] + bn[nt];
            s_ = fmaf(hvv, hvv, s_);
          }
          er[r] = s_;
        }
        #pragma unroll
        for (int x2 = 1; x2 < 16; x2 <<= 1){
          #pragma unroll
          for (int r = 0; r < 4; r++) er[r] += __shfl_xor(er[r], x2, 64);
        }
        if (l15 == 0){
          #pragma unroll
          for (int r = 0; r < 4; r++){
            int ei = mt * 16 + quad * 4 + r;
            sm.energy[ei] = (ng == 0) ? er[r] : (sm.energy[ei] + er[r]);
          }
        }
      }
      __syncthreads();   // waitcnt fence; also pins pass boundaries (spill guard)
    }
  }

  // argmax over 81 energies (padded rows >80 contain garbage correlations — mask them)
  float bv = sm.energy[lane]; int bi = lane;
  {
    int s2 = lane + 64;
    if (s2 < 81){
      float v2 = sm.energy[s2];
      if (v2 > bv){ bv = v2; bi = s2; }   // ascending index: ties keep lower
    }
  }
  int ind = waveArgMax(bv, bi);

  // recompute selected row h[ind, j] EXACTLY in fp32 for this lane's 4 js
  int roff = 80 - ind;
  float hv[4];
  #pragma unroll
  for (int q = 0; q < 4; q++) hv[q] = sm.beL[lane + 64 * q];
  for (int w2 = 0; w2 < 80; w2++){
    float xv = sm.xp[80 + w2];
    const float* row = We + (w2 + roff) * 256;
    #pragma unroll
    for (int q = 0; q < 4; q++) hv[q] = fmaf(xv, row[lane + 64 * q], hv[q]);
  }

  // hsr (per lane's 4 js)
  float vsq[4];
  #pragma unroll
  for (int q = 0; q < 4; q++){ vsq[q] = hv[q] * hv[q]; sm.hsq[lane + 64 * q] = vsq[q]; }
  __syncthreads();
  int sel1[4];
  rankTop64w(sm, vsq, lane, sel1);
  float mpv[4];
  #pragma unroll
  for (int q = 0; q < 4; q++) mpv[q] = mask[lane + 64 * q];
  if (first){
    #pragma unroll
    for (int q = 0; q < 4; q++){
      int j = lane + 64 * q;
      mask[j] = (float)sel1[q];
      sm.hsel[j] = sel1[q] ? hv[q] : 0.f;
    }
  } else {
    int st = sm.smask_t;
    float h2[4];
    #pragma unroll
    for (int q = 0; q < 4; q++){
      float interv = mpv[q] * (float)sel1[q];
      if (interv > 0.f && !st){
        float dd = hv[q] - (1.f - interv);
        lossAcc += dd * dd;
      }
      h2[q] = (mpv[q] > 0.f) ? 0.f : hv[q];
    }
    __syncthreads();               // rank1 readers done before hsq rewrite
    float vsq2[4];
    #pragma unroll
    for (int q = 0; q < 4; q++){ vsq2[q] = h2[q] * h2[q]; sm.hsq[lane + 64 * q] = vsq2[q]; }
    __syncthreads();
    int sel2[4];
    rankTop64w(sm, vsq2, lane, sel2);
    #pragma unroll
    for (int q = 0; q < 4; q++){
      int j = lane + 64 * q;
      mask[j] = mpv[q] + (float)sel2[q];
      sm.hsel[j] = sel2[q] ? h2[q] : 0.f;
    }
  }
  __syncthreads();                 // hsel ready

  // decode: ext[d] = bdec[d] + sum_h hsel[h]*Wdec[h*160+d]; lane owns d, d+64, d+128
  {
    int dc = 128 + (lane & 31);    // clamped third output (discarded for lane>=32)
    float a0 = bdec[lane], a1 = bdec[lane + 64], a2 = bdec[dc];
    const float4* h4 = (const float4*)sm.hsel;
    for (int hi = 0; hi < 64; hi++){
      float4 hh = h4[hi];          // wave-uniform broadcast
      const float* r0 = Wdec + (hi * 4 + 0) * 160;
      const float* r1 = Wdec + (hi * 4 + 1) * 160;
      const float* r2 = Wdec + (hi * 4 + 2) * 160;
      const float* r3 = Wdec + (hi * 4 + 3) * 160;
      a0 = fmaf(hh.x, r0[lane], a0);       a1 = fmaf(hh.x, r0[lane + 64], a1);  a2 = fmaf(hh.x, r0[dc], a2);
      a0 = fmaf(hh.y, r1[lane], a0);       a1 = fmaf(hh.y, r1[lane + 64], a1);  a2 = fmaf(hh.y, r1[dc], a2);
      a0 = fmaf(hh.z, r2[lane], a0);       a1 = fmaf(hh.z, r2[lane + 64], a1);  a2 = fmaf(hh.z, r2[dc], a2);
      a0 = fmaf(hh.w, r3[lane], a0);       a1 = fmaf(hh.w, r3[lane + 64], a1);  a2 = fmaf(hh.w, r3[dc], a2);
    }
    sm.ext[lane] = a0;
    sm.ext[lane + 64] = a1;
    if (lane < 32) sm.ext[128 + lane] = a2;
  }
  __syncthreads();

  float mv = fabsf((float)(theta - 79));
  bool gate = (mv > 40.0f);        // ETH
  for (int d = lane; d < 80; d += 64){
    float dec = sm.ext[ind + d];
    dec_out[d] = dec;              // residual update uses decoded output regardless of gates
    float diff = dec - target[d];
    float l = (gate || sm.smask[d]) ? 0.f : diff * diff;
    lossAcc += l / (mv + 1.0f);
  }
  __syncthreads();
}

__global__ void __launch_bounds__(64) zero_out_kernel(float* out){
  if (threadIdx.x == 0) out[0] = 0.f;
}

// Pre-repack We into MFMA B-fragment layout (bf16 hi and lo), one 16B frag per lane per tile.
__global__ void __launch_bounds__(64) prep_we_kernel(
    const float* __restrict__ We, short8* __restrict__ bh, short8* __restrict__ bl){
  int tile = blockIdx.x;
  int lane = threadIdx.x;
  int kt = tile >> 4, nt = tile & 15;
  int k0 = kt * 32 + (lane >> 4) * 8;
  int n  = nt * 16 + (lane & 15);
  short8 h, l;
  #pragma unroll
  for (int j = 0; j < 8; j++){
    float v = We[(k0 + j) * 256 + n];
    unsigned bits = __float_as_uint(v);
    unsigned hi = bits >> 16;
    float hif = __uint_as_float(hi << 16);
    unsigned lo = __float_as_uint(v - hif) >> 16;
    h[j] = (short)hi; l[j] = (short)lo;
  }
  bh[tile * 64 + lane] = h;
  bl[tile * 64 + lane] = l;
}

template<int USE_WS>
__global__ void __launch_bounds__(64, 2) net_kernel(
    const float* __restrict__ x,  const float* __restrict__ y,
    const float* __restrict__ We, const float* __restrict__ be,
    const float* __restrict__ Wd, const float* __restrict__ bd,
    const float* __restrict__ Wds,const float* __restrict__ bds,
    const short8* __restrict__ wsBh, const short8* __restrict__ wsBl,
    float* out)
{
  __shared__ SM sm;
  int lane = threadIdx.x;
  int bt  = blockIdx.x;
  const float* xin = x + bt * 80;
  const float* yin = y + bt * 80;

  for (int i = lane; i < 80; i += 64){
    sm.xres[i] = xin[i];
    float yv = yin[i];
    sm.yres[i] = yv;
    sm.smask[i] = (yv == 0.f) ? 1 : 0;   // seq_mask from ORIGINAL y
  }
  for (int i = lane; i < 256; i += 64){
    sm.mp_self[i] = 0.f;
    sm.mp_src[i]  = 0.f;
    sm.beL[i] = be[i];
  }
  __syncthreads();
  {
    int c = 0;
    for (int i = lane; i < 80; i += 64) c += (int)sm.smask[i];
    int total = waveSumI(c);
    if (lane == 0) sm.smask_t = (total == 80) ? 1 : 0;
  }
  __syncthreads();

  float lossAcc = 0.f;

  for (int it = 0; it < 4; it++){
    bool first = (it == 0);

    // --- align x_res to y_res ---
    int th1 = simArgmax(sm, sm.xres, sm.yal);

    // --- attention softmax(y_al * y_res) and z = y_al * attn ---
    {
      float p0 = sm.yal[lane] * sm.yres[lane];
      float p1 = (lane < 16) ? sm.yal[64 + lane] * sm.yres[64 + lane] : -INFINITY;
      float mx = waveMax(fmaxf(p0, p1));
      float e0 = expf(p0 - mx);
      float e1 = (lane < 16) ? expf(p1 - mx) : 0.f;
      float ssum = waveSum(e0 + e1);
      sm.zb[lane] = sm.yal[lane] * (e0 / ssum);
      if (lane < 16) sm.zb[64 + lane] = sm.yal[64 + lane] * (e1 / ssum);
    }
    __syncthreads();

    // --- reverse shift: x_ele[d] = z[d + 79 - theta] ---
    for (int d = lane; d < 80; d += 64){
      int q = d + 79 - th1;
      sm.xele[d] = (q >= 0 && q < 80) ? sm.zb[q] : 0.f;
    }

    // --- self branch ---
    branchCompute<USE_WS>(sm, We, wsBh, wsBl, Wds, bds,
                          sm.xele, sm.mp_self, sm.xres, sm.xele, th1, first, lossAcc);

    // --- re-align decoded x_ele to y_res ---
    int th2 = simArgmax(sm, sm.xele, sm.yal);

    // --- src branch ---
    branchCompute<USE_WS>(sm, We, wsBh, wsBl, Wd, bd,
                          sm.yal, sm.mp_src, sm.yres, sm.decsrc, th2, first, lossAcc);

    // --- residual updates ---
    __syncthreads();
    for (int d = lane; d < 80; d += 64){
      sm.xres[d] -= sm.xele[d];
      sm.yres[d] -= sm.decsrc[d];
    }
    __syncthreads();
  }

  float total = waveSum(lossAcc);
  if (lane == 0) atomicAdd(out, total * 0.25f);   // mean over 4 iterations
}

extern "C" void kernel_launch(void* const* d_in, const int* in_sizes, int n_in,
                              void* d_out, int out_size, void* d_ws, size_t ws_size,
                              hipStream_t stream) {
  const float* x   = (const float*)d_in[0];
  const float* y   = (const float*)d_in[1];
  const float* We  = (const float*)d_in[2];
  const float* be  = (const float*)d_in[3];
  const float* Wd  = (const float*)d_in[4];
  const float* bd  = (const float*)d_in[5];
  const float* Wds = (const float*)d_in[6];
  const float* bds = (const float*)d_in[7];
  float* out = (float*)d_out;

  // We-fragment repack buffers: 80 tiles x 64 lanes x 16B each for hi and lo
  const size_t fragCount = 80 * 64;                     // short8 elements per buffer
  const size_t fragBytes = fragCount * sizeof(short8);  // 81920 B
  int use_ws = (ws_size >= 2 * fragBytes) ? 1 : 0;
  short8* wsBh = (short8*)d_ws;
  short8* wsBl = wsBh + fragCount;

  hipLaunchKernelGGL(zero_out_kernel, dim3(1), dim3(64), 0, stream, out);
  if (use_ws){
    hipLaunchKernelGGL(prep_we_kernel, dim3(80), dim3(64), 0, stream, We, wsBh, wsBl);
    hipLaunchKernelGGL((net_kernel<1>), dim3(NBT), dim3(64), 0, stream,
                       x, y, We, be, Wd, bd, Wds, bds, wsBh, wsBl, out);
  } else {
    hipLaunchKernelGGL((net_kernel<0>), dim3(NBT), dim3(64), 0, stream,
                       x, y, We, be, Wd, bd, Wds, bds, wsBh, wsBl, out);
  }
}

// Round 7
// 923.565 us; speedup vs baseline: 4.0590x; 1.0724x over previous
//
#include <hip/hip_runtime.h>
#include <math.h>

// Problem constants (B=8, T=256 -> 2048 independent (b,t) pipelines)
// Structure: ONE WAVE (64 threads) per pipeline; no inter-wave barriers.
// R7: decode skips the 192 exactly-zero hsel rows (bit-exact), 4x fewer
// global loads/fmafs on the decode chain.
#define NBT 2048

typedef __attribute__((ext_vector_type(8))) short short8;     // 8 bf16 (4 VGPRs)
typedef __attribute__((ext_vector_type(4))) float floatx4;    // MFMA C/D

struct SM {
  alignas(16) float xp[240];      // zero-padded encoder input (nonzero in [80,160))
  alignas(16) unsigned xhl[256];  // packed bf16: hi | lo<<16, zero-padded to 256
  alignas(16) float hsq[256];     // h^2 for top-64 ranking
  alignas(16) float yres[80];
  alignas(16) float beL[256];     // encoder bias staged in LDS
  alignas(16) float spad[240];    // padded buffer for sim windows
  alignas(16) float dval[64];     // compacted selected hidden values (ascending idx)
  alignas(16) int   dlist[64];    // compacted selected hidden indices (ascending)
  float xres[80];
  float yal[80];
  float xele[80];
  float decsrc[80];
  float zb[80];
  float energy[96];               // 81 valid + pad (6 m-tiles of 16)
  float mp_self[256];
  float mp_src[256];
  float ext[160];
  unsigned char smask[80];
  int smask_t;
};

// ---- wave-level primitives (64 lanes, butterfly -> all lanes hold result) ----
__device__ __forceinline__ float waveSum(float v){
  #pragma unroll
  for (int off = 32; off > 0; off >>= 1) v += __shfl_xor(v, off, 64);
  return v;
}
__device__ __forceinline__ int waveSumI(int v){
  #pragma unroll
  for (int off = 32; off > 0; off >>= 1) v += __shfl_xor(v, off, 64);
  return v;
}
__device__ __forceinline__ float waveMax(float v){
  #pragma unroll
  for (int off = 32; off > 0; off >>= 1) v = fmaxf(v, __shfl_xor(v, off, 64));
  return v;
}
// argmax with JAX tie rule: first (lowest index) max wins; symmetric butterfly
__device__ __forceinline__ int waveArgMax(float v, int idx){
  #pragma unroll
  for (int off = 32; off > 0; off >>= 1){
    float ov = __shfl_xor(v,   off, 64);
    int   oi = __shfl_xor(idx, off, 64);
    if (ov > v || (ov == v && oi < idx)){ v = ov; idx = oi; }
  }
  return idx;
}

// top-64 membership via rank for this lane's 4 hidden units (j = lane + 64q).
// rank = #{i: v_i > v_j} + #{i<j: v_i == v_j}; selected iff rank < 64.
// hsq[i4] reads are wave-uniform -> LDS broadcast, conflict-free.
__device__ __forceinline__ void rankTop64w(SM& sm, const float vsq[4], int lane, int sel[4]){
  int cnt[4] = {0,0,0,0};
  const float4* q4 = (const float4*)sm.hsq;
  #pragma unroll 4
  for (int i4 = 0; i4 < 64; i4++){
    float4 o = q4[i4];
    int ib = i4 * 4;
    #pragma unroll
    for (int q = 0; q < 4; q++){
      int j = lane + 64 * q;
      cnt[q] += (o.x > vsq[q] || (o.x == vsq[q] && (ib + 0) < j)) ? 1 : 0;
      cnt[q] += (o.y > vsq[q] || (o.y == vsq[q] && (ib + 1) < j)) ? 1 : 0;
      cnt[q] += (o.z > vsq[q] || (o.z == vsq[q] && (ib + 2) < j)) ? 1 : 0;
      cnt[q] += (o.w > vsq[q] || (o.w == vsq[q] && (ib + 3) < j)) ? 1 : 0;
    }
  }
  #pragma unroll
  for (int q = 0; q < 4; q++) sel[q] = (cnt[q] < 64) ? 1 : 0;
}

// Compact the exactly-64 selected (index,value) pairs into ascending-index LDS
// lists via wave ballots. Ascending order => decode accumulation order matches
// the reference (skipped entries are exact zeros: fmaf(0,w,a)==a bit-exactly).
__device__ __forceinline__ void compactSel(SM& sm, const int sel[4], const float val[4], int lane){
  unsigned long long mq[4];
  #pragma unroll
  for (int q = 0; q < 4; q++) mq[q] = __ballot(sel[q] != 0);
  int base1 = __popcll(mq[0]);
  int base2 = base1 + __popcll(mq[1]);
  int base3 = base2 + __popcll(mq[2]);
  int base[4] = {0, base1, base2, base3};
  unsigned long long below = (lane == 0) ? 0ull : ((~0ull) >> (64 - lane));
  #pragma unroll
  for (int q = 0; q < 4; q++){
    if (sel[q]){
      int pos = base[q] + (int)__popcll(mq[q] & below);
      sm.dlist[pos] = lane + 64 * q;
      sm.dval[pos]  = val[q];
    }
  }
}

// sim_argmax: cosine sim over 159 shifts of src vs yres; each lane owns shifts
// {lane, lane+64, lane+128}. Per-candidate fmaf chain order preserved.
__device__ __forceinline__ int simArgmax(SM& sm, const float* src, float* yal_out){
  int lane = threadIdx.x;
  __syncthreads();
  for (int i = lane; i < 240; i += 64)
    sm.spad[i] = (i >= 79 && i < 159) ? src[i - 79] : 0.f;
  __syncthreads();
  float yv2 = 0.f;
  for (int w = lane; w < 80; w += 64){ float yv = sm.yres[w]; yv2 = fmaf(yv, yv, yv2); }
  float nys = sqrtf(waveSum(yv2));

  int   sidx[3]; int svalid[3];
  #pragma unroll
  for (int c = 0; c < 3; c++){
    int s = lane + 64 * c;
    svalid[c] = (s < 159);
    sidx[c] = svalid[c] ? s : 0;      // clamp to keep reads in-bounds
  }
  float num[3] = {0.f,0.f,0.f}, nx[3] = {0.f,0.f,0.f};
  const float4* y4p = (const float4*)sm.yres;
  for (int w4 = 0; w4 < 20; w4++){
    float4 yy = y4p[w4];
    int w = w4 * 4;
    #pragma unroll
    for (int c = 0; c < 3; c++){
      float xa0 = sm.spad[sidx[c] + w + 0];
      float xa1 = sm.spad[sidx[c] + w + 1];
      float xa2 = sm.spad[sidx[c] + w + 2];
      float xa3 = sm.spad[sidx[c] + w + 3];
      num[c] = fmaf(xa0, yy.x, num[c]); nx[c] = fmaf(xa0, xa0, nx[c]);
      num[c] = fmaf(xa1, yy.y, num[c]); nx[c] = fmaf(xa1, xa1, nx[c]);
      num[c] = fmaf(xa2, yy.z, num[c]); nx[c] = fmaf(xa2, xa2, nx[c]);
      num[c] = fmaf(xa3, yy.w, num[c]); nx[c] = fmaf(xa3, xa3, nx[c]);
    }
  }
  float bv = -INFINITY; int bi = 0;
  #pragma unroll
  for (int c = 0; c < 3; c++){          // ascending index: strict > keeps lowest idx on ties
    if (svalid[c]){
      float simv = num[c] / (sqrtf(nx[c]) * nys + 1e-6f);
      if (simv > bv){ bv = simv; bi = lane + 64 * c; }
    }
  }
  int th = waveArgMax(bv, bi);
  for (int i = lane; i < 80; i += 64) yal_out[i] = sm.spad[th + i];
  __syncthreads();
  return th;
}

// One branch: MFMA energy (split bf16, kt-trimmed to nonzero support — bit-safe),
// argmax, exact fp32 row recompute, hsr, sparse decode, masked loss.
template<int USE_WS>
__device__ __forceinline__ void branchCompute(
    SM& sm, const float* __restrict__ We,
    const short8* __restrict__ wsBh, const short8* __restrict__ wsBl,
    const float* __restrict__ Wdec, const float* __restrict__ bdec,
    const float* enc_in, float* mask, const float* target,
    float* dec_out, int theta, bool first, float& lossAcc)
{
  int lane = threadIdx.x;
  int quad = lane >> 4, l15 = lane & 15;
  __syncthreads();
  for (int i = lane; i < 256; i += 64){
    float v = (i >= 80 && i < 160) ? enc_in[i - 80] : 0.f;
    if (i < 240) sm.xp[i] = v;
    unsigned bits = __float_as_uint(v);
    unsigned hi = bits >> 16;
    float hif = __uint_as_float(hi << 16);
    unsigned lo = __float_as_uint(v - hif) >> 16;
    sm.xhl[i] = hi | (lo << 16);
  }
  __syncthreads();

  const floatx4 zero4 = {0.f, 0.f, 0.f, 0.f};

  #pragma unroll 1
  for (int mh = 0; mh < 3; mh++){        // 2 m-tiles per pass (acc = 32 VGPR)
    int ktlo = (mh == 0) ? 1 : 0;        // nonzero-support kt range for these m rows
    int kthi = 5 - mh;
    #pragma unroll 1
    for (int ng = 0; ng < 4; ng++){      // 4 n-tiles per pass
      floatx4 acc[2][4];
      #pragma unroll
      for (int m2 = 0; m2 < 2; m2++)
        #pragma unroll
        for (int nt = 0; nt < 4; nt++) acc[m2][nt] = zero4;

      #pragma unroll
      for (int kt = 0; kt < 5; kt++){
        if (kt < ktlo || kt >= kthi) continue;   // wave-uniform scalar skip; removed
                                                 // products are exactly 0 -> bit-safe
        short8 Bh[4], Bl[4];
        #pragma unroll
        for (int nt = 0; nt < 4; nt++){
          int tileIdx = kt * 16 + (ng * 4 + nt);
          if (USE_WS){
            Bh[nt] = wsBh[tileIdx * 64 + lane];
            Bl[nt] = wsBl[tileIdx * 64 + lane];
          } else {
            short8 bh, bl;
            int k0 = kt * 32 + quad * 8;
            int n  = (ng * 4 + nt) * 16 + l15;
            #pragma unroll
            for (int j = 0; j < 8; j++){
              float v = We[(k0 + j) * 256 + n];
              unsigned bits = __float_as_uint(v);
              unsigned hi = bits >> 16;
              float hif = __uint_as_float(hi << 16);
              unsigned lo = __float_as_uint(v - hif) >> 16;
              bh[j] = (short)hi; bl[j] = (short)lo;
            }
            Bh[nt] = bh; Bl[nt] = bl;
          }
        }
        short8 Ah[2], Al[2];
        #pragma unroll
        for (int m2 = 0; m2 < 2; m2++){
          int mt = mh * 2 + m2;
          int base = mt * 16 + l15 + kt * 32 + quad * 8;
          short8 ah, al;
          #pragma unroll
          for (int j = 0; j < 8; j++){
            unsigned u = sm.xhl[base + j];
            ah[j] = (short)(u & 0xffffu);
            al[j] = (short)(u >> 16);
          }
          Ah[m2] = ah; Al[m2] = al;
        }
        #pragma unroll
        for (int m2 = 0; m2 < 2; m2++)
          #pragma unroll
          for (int nt = 0; nt < 4; nt++){
            acc[m2][nt] = __builtin_amdgcn_mfma_f32_16x16x32_bf16(Ah[m2], Bh[nt], acc[m2][nt], 0, 0, 0);
            acc[m2][nt] = __builtin_amdgcn_mfma_f32_16x16x32_bf16(Al[m2], Bh[nt], acc[m2][nt], 0, 0, 0);
            acc[m2][nt] = __builtin_amdgcn_mfma_f32_16x16x32_bf16(Ah[m2], Bl[nt], acc[m2][nt], 0, 0, 0);
          }
      }

      // epilogue: add bias, square, reduce over this pass's 64 columns (l15 butterfly)
      float bn[4];
      #pragma unroll
      for (int nt = 0; nt < 4; nt++) bn[nt] = sm.beL[(ng * 4 + nt) * 16 + l15];
      #pragma unroll
      for (int m2 = 0; m2 < 2; m2++){
        int mt = mh * 2 + m2;
        float er[4];
        #pragma unroll
        for (int r = 0; r < 4; r++){
          float s_ = 0.f;
          #pragma unroll
          for (int nt = 0; nt < 4; nt++){
            float hvv = acc[m2][nt][r] + bn[nt];
            s_ = fmaf(hvv, hvv, s_);
          }
          er[r] = s_;
        }
        #pragma unroll
        for (int x2 = 1; x2 < 16; x2 <<= 1){
          #pragma unroll
          for (int r = 0; r < 4; r++) er[r] += __shfl_xor(er[r], x2, 64);
        }
        if (l15 == 0){
          #pragma unroll
          for (int r = 0; r < 4; r++){
            int ei = mt * 16 + quad * 4 + r;
            sm.energy[ei] = (ng == 0) ? er[r] : (sm.energy[ei] + er[r]);
          }
        }
      }
      __syncthreads();   // waitcnt fence; also pins pass boundaries (spill guard)
    }
  }

  // argmax over 81 energies (padded rows >80 contain garbage correlations — mask them)
  float bv = sm.energy[lane]; int bi = lane;
  {
    int s2 = lane + 64;
    if (s2 < 81){
      float v2 = sm.energy[s2];
      if (v2 > bv){ bv = v2; bi = s2; }   // ascending index: ties keep lower
    }
  }
  int ind = waveArgMax(bv, bi);

  // recompute selected row h[ind, j] EXACTLY in fp32 for this lane's 4 js
  int roff = 80 - ind;
  float hv[4];
  #pragma unroll
  for (int q = 0; q < 4; q++) hv[q] = sm.beL[lane + 64 * q];
  #pragma unroll 4
  for (int w2 = 0; w2 < 80; w2++){
    float xv = sm.xp[80 + w2];
    const float* row = We + (w2 + roff) * 256;
    #pragma unroll
    for (int q = 0; q < 4; q++) hv[q] = fmaf(xv, row[lane + 64 * q], hv[q]);
  }

  // hsr (per lane's 4 js)
  float vsq[4];
  #pragma unroll
  for (int q = 0; q < 4; q++){ vsq[q] = hv[q] * hv[q]; sm.hsq[lane + 64 * q] = vsq[q]; }
  __syncthreads();
  int sel1[4];
  rankTop64w(sm, vsq, lane, sel1);
  float mpv[4];
  #pragma unroll
  for (int q = 0; q < 4; q++) mpv[q] = mask[lane + 64 * q];
  if (first){
    #pragma unroll
    for (int q = 0; q < 4; q++)
      mask[lane + 64 * q] = (float)sel1[q];
    compactSel(sm, sel1, hv, lane);
  } else {
    int st = sm.smask_t;
    float h2[4];
    #pragma unroll
    for (int q = 0; q < 4; q++){
      float interv = mpv[q] * (float)sel1[q];
      if (interv > 0.f && !st){
        float dd = hv[q] - (1.f - interv);
        lossAcc += dd * dd;
      }
      h2[q] = (mpv[q] > 0.f) ? 0.f : hv[q];
    }
    __syncthreads();               // rank1 readers done before hsq rewrite
    float vsq2[4];
    #pragma unroll
    for (int q = 0; q < 4; q++){ vsq2[q] = h2[q] * h2[q]; sm.hsq[lane + 64 * q] = vsq2[q]; }
    __syncthreads();
    int sel2[4];
    rankTop64w(sm, vsq2, lane, sel2);
    #pragma unroll
    for (int q = 0; q < 4; q++)
      mask[lane + 64 * q] = mpv[q] + (float)sel2[q];
    compactSel(sm, sel2, h2, lane);
  }
  __syncthreads();                 // compact list ready

  // sparse decode over the exactly-64 selected rows (ascending idx => bit-exact):
  // ext[d] = bdec[d] + sum_{sel h asc} val_h * Wdec[h*160+d]; lane owns d, d+64, d+128
  {
    int dc = 128 + (lane & 31);    // clamped third output (discarded for lane>=32)
    float a0 = bdec[lane], a1 = bdec[lane + 64], a2 = bdec[dc];
    #pragma unroll 8
    for (int i = 0; i < 64; i++){
      int idx = sm.dlist[i];       // wave-uniform broadcast
      float hval = sm.dval[i];
      const float* r = Wdec + idx * 160;
      a0 = fmaf(hval, r[lane], a0);
      a1 = fmaf(hval, r[lane + 64], a1);
      a2 = fmaf(hval, r[dc], a2);
    }
    sm.ext[lane] = a0;
    sm.ext[lane + 64] = a1;
    if (lane < 32) sm.ext[128 + lane] = a2;
  }
  __syncthreads();

  float mv = fabsf((float)(theta - 79));
  bool gate = (mv > 40.0f);        // ETH
  for (int d = lane; d < 80; d += 64){
    float dec = sm.ext[ind + d];
    dec_out[d] = dec;              // residual update uses decoded output regardless of gates
    float diff = dec - target[d];
    float l = (gate || sm.smask[d]) ? 0.f : diff * diff;
    lossAcc += l / (mv + 1.0f);
  }
  __syncthreads();
}

__global__ void __launch_bounds__(64) zero_out_kernel(float* out){
  if (threadIdx.x == 0) out[0] = 0.f;
}

// Pre-repack We into MFMA B-fragment layout (bf16 hi and lo), one 16B frag per lane per tile.
__global__ void __launch_bounds__(64) prep_we_kernel(
    const float* __restrict__ We, short8* __restrict__ bh, short8* __restrict__ bl){
  int tile = blockIdx.x;
  int lane = threadIdx.x;
  int kt = tile >> 4, nt = tile & 15;
  int k0 = kt * 32 + (lane >> 4) * 8;
  int n  = nt * 16 + (lane & 15);
  short8 h, l;
  #pragma unroll
  for (int j = 0; j < 8; j++){
    float v = We[(k0 + j) * 256 + n];
    unsigned bits = __float_as_uint(v);
    unsigned hi = bits >> 16;
    float hif = __uint_as_float(hi << 16);
    unsigned lo = __float_as_uint(v - hif) >> 16;
    h[j] = (short)hi; l[j] = (short)lo;
  }
  bh[tile * 64 + lane] = h;
  bl[tile * 64 + lane] = l;
}

template<int USE_WS>
__global__ void __launch_bounds__(64, 2) net_kernel(
    const float* __restrict__ x,  const float* __restrict__ y,
    const float* __restrict__ We, const float* __restrict__ be,
    const float* __restrict__ Wd, const float* __restrict__ bd,
    const float* __restrict__ Wds,const float* __restrict__ bds,
    const short8* __restrict__ wsBh, const short8* __restrict__ wsBl,
    float* out)
{
  __shared__ SM sm;
  int lane = threadIdx.x;
  int bt  = blockIdx.x;
  const float* xin = x + bt * 80;
  const float* yin = y + bt * 80;

  for (int i = lane; i < 80; i += 64){
    sm.xres[i] = xin[i];
    float yv = yin[i];
    sm.yres[i] = yv;
    sm.smask[i] = (yv == 0.f) ? 1 : 0;   // seq_mask from ORIGINAL y
  }
  for (int i = lane; i < 256; i += 64){
    sm.mp_self[i] = 0.f;
    sm.mp_src[i]  = 0.f;
    sm.beL[i] = be[i];
  }
  __syncthreads();
  {
    int c = 0;
    for (int i = lane; i < 80; i += 64) c += (int)sm.smask[i];
    int total = waveSumI(c);
    if (lane == 0) sm.smask_t = (total == 80) ? 1 : 0;
  }
  __syncthreads();

  float lossAcc = 0.f;

  for (int it = 0; it < 4; it++){
    bool first = (it == 0);

    // --- align x_res to y_res ---
    int th1 = simArgmax(sm, sm.xres, sm.yal);

    // --- attention softmax(y_al * y_res) and z = y_al * attn ---
    {
      float p0 = sm.yal[lane] * sm.yres[lane];
      float p1 = (lane < 16) ? sm.yal[64 + lane] * sm.yres[64 + lane] : -INFINITY;
      float mx = waveMax(fmaxf(p0, p1));
      float e0 = expf(p0 - mx);
      float e1 = (lane < 16) ? expf(p1 - mx) : 0.f;
      float ssum = waveSum(e0 + e1);
      sm.zb[lane] = sm.yal[lane] * (e0 / ssum);
      if (lane < 16) sm.zb[64 + lane] = sm.yal[64 + lane] * (e1 / ssum);
    }
    __syncthreads();

    // --- reverse shift: x_ele[d] = z[d + 79 - theta] ---
    for (int d = lane; d < 80; d += 64){
      int q = d + 79 - th1;
      sm.xele[d] = (q >= 0 && q < 80) ? sm.zb[q] : 0.f;
    }

    // --- self branch ---
    branchCompute<USE_WS>(sm, We, wsBh, wsBl, Wds, bds,
                          sm.xele, sm.mp_self, sm.xres, sm.xele, th1, first, lossAcc);

    // --- re-align decoded x_ele to y_res ---
    int th2 = simArgmax(sm, sm.xele, sm.yal);

    // --- src branch ---
    branchCompute<USE_WS>(sm, We, wsBh, wsBl, Wd, bd,
                          sm.yal, sm.mp_src, sm.yres, sm.decsrc, th2, first, lossAcc);

    // --- residual updates ---
    __syncthreads();
    for (int d = lane; d < 80; d += 64){
      sm.xres[d] -= sm.xele[d];
      sm.yres[d] -= sm.decsrc[d];
    }
    __syncthreads();
  }

  float total = waveSum(lossAcc);
  if (lane == 0) atomicAdd(out, total * 0.25f);   // mean over 4 iterations
}

extern "C" void kernel_launch(void* const* d_in, const int* in_sizes, int n_in,
                              void* d_out, int out_size, void* d_ws, size_t ws_size,
                              hipStream_t stream) {
  const float* x   = (const float*)d_in[0];
  const float* y   = (const float*)d_in[1];
  const float* We  = (const float*)d_in[2];
  const float* be  = (const float*)d_in[3];
  const float* Wd  = (const float*)d_in[4];
  const float* bd  = (const float*)d_in[5];
  const float* Wds = (const float*)d_in[6];
  const float* bds = (const float*)d_in[7];
  float* out = (float*)d_out;

  // We-fragment repack buffers: 80 tiles x 64 lanes x 16B each for hi and lo
  const size_t fragCount = 80 * 64;                     // short8 elements per buffer
  const size_t fragBytes = fragCount * sizeof(short8);  // 81920 B
  int use_ws = (ws_size >= 2 * fragBytes) ? 1 : 0;
  short8* wsBh = (short8*)d_ws;
  short8* wsBl = wsBh + fragCount;

  hipLaunchKernelGGL(zero_out_kernel, dim3(1), dim3(64), 0, stream, out);
  if (use_ws){
    hipLaunchKernelGGL(prep_we_kernel, dim3(80), dim3(64), 0, stream, We, wsBh, wsBl);
    hipLaunchKernelGGL((net_kernel<1>), dim3(NBT), dim3(64), 0, stream,
                       x, y, We, be, Wd, bd, Wds, bds, wsBh, wsBl, out);
  } else {
    hipLaunchKernelGGL((net_kernel<0>), dim3(NBT), dim3(64), 0, stream,
                       x, y, We, be, Wd, bd, Wds, bds, wsBh, wsBl, out);
  }
}